// Round 5
// baseline (168.545 us; speedup 1.0000x reference)
//
#include <hip/hip_runtime.h>

#define N_TOKENS 32768
#define K_CODES  1024
#define DIM      256
#define BETA     0.25f

typedef unsigned long long u64;
typedef _Float16 half8 __attribute__((ext_vector_type(8)));
typedef float floatx4 __attribute__((ext_vector_type(4)));

// ---- init: wn[k]=||w_k||^2 (fp32 exact), counts=0, keys=+inf, w->hi/lo fp16 --
__global__ void init_kernel(const float* __restrict__ w, float* __restrict__ wn,
                            int* __restrict__ counts, u64* __restrict__ keys,
                            _Float16* __restrict__ whiG, _Float16* __restrict__ wloG) {
    int k = blockIdx.x;
    int lane = threadIdx.x;  // 64
    float4 v = *(const float4*)(w + (size_t)k * DIM + lane * 4);
    float vals[4] = {v.x, v.y, v.z, v.w};
    float s = 0.f;
    #pragma unroll
    for (int e = 0; e < 4; e++) {
        s += vals[e] * vals[e];
        _Float16 h = (_Float16)vals[e];
        whiG[k * DIM + lane * 4 + e] = h;
        wloG[k * DIM + lane * 4 + e] = (_Float16)(vals[e] - (float)h);
    }
    #pragma unroll
    for (int off = 32; off; off >>= 1) s += __shfl_down(s, off);
    if (lane == 0) { wn[k] = s; counts[k] = 0; }
    if (lane < 32) keys[k * 32 + lane] = ~0ull;   // 1024*32 = 32768 keys
}

// ---------------- argmin: fp16-split MFMA distance GEMM + atomicMin merge ----
// dot(z,w) = hi_z*hi_w + hi_z*lo_w + lo_z*hi_w  (lo*lo dropped, err ~1e-5).
// grid = 4 code-quarters x 256 token-tiles. Block: 128 tok x 256 codes,
// 4 waves, wave tile 64x128.
// Round-5 restructure (r4 budget: MFMA floor 24.8us, LDS pipe ~33us, measured
// 62us => LDS-bound + barrier-serialized, NOT schedule-bound):
//  - z NEVER staged to LDS: A fragments load direct from global (L2/L3-hot,
//    8 fp32/lane per i) and hi/lo-split in regs. Kills z-writes + A-reads
//    (1/3 of LDS traffic) and the convert in the serial phase. wq-pair waves
//    duplicate A loads (2x) -- absorbed by L2, VALU has headroom.
//  - w double-buffered (2x32KB, 64KB total -> still 2 blocks/CU), loads for
//    dt+1 issued before the MFMA block, ds_writes mid-j-loop (32-VGPR short
//    lifetime, not r3's 48-reg-across-block wall), ONE barrier per chunk.
//  - w rows 64B with XOR swizzle byte^=(row&3)<<4: structural 8-words/bank
//    minimum on both ds_write_b128 and ds_read_b128 (verified by bank map).
// New ceiling: max(MFMA 24.8, LDS ~15) ~= 25us + latency slack.
__global__ __launch_bounds__(256, 2) void argmin_kernel(
    const float* __restrict__ z, const _Float16* __restrict__ whiG,
    const _Float16* __restrict__ wloG, const float* __restrict__ wn,
    u64* __restrict__ keys)
{
    __shared__ __attribute__((aligned(16))) char wbuf[2][32768];

    const int tid  = threadIdx.x;
    const int lane = tid & 63;
    const int wid  = tid >> 6;          // 0..3
    const int wm   = wid >> 1;          // token half (64)
    const int wq   = wid & 1;           // code half (128)
    const int t_   = blockIdx.x & 255;  // token tile
    const int q    = blockIdx.x >> 8;   // code quarter 0..3
    const int tok0  = t_ * 128;
    const int kbase = q * 256;

    // ||w||^2 for this thread's 8 epilogue columns -> registers
    float wnr[8];
    #pragma unroll
    for (int j = 0; j < 8; j++)
        wnr[j] = wn[kbase + wq * 128 + j * 16 + (lane & 15)];

    floatx4 acc[4][8];
    #pragma unroll
    for (int i = 0; i < 4; i++)
        #pragma unroll
        for (int j = 0; j < 8; j++)
            acc[i][j] = (floatx4){0.f, 0.f, 0.f, 0.f};

    // ---- w staging addressing (thread covers rows r0+s*64, 8-half group g0)
    const int r0 = tid >> 2;            // 0..63
    const int g0 = tid & 3;
    // row t=r0+s*64: byte = t*64 + (g0*16 ^ ((t&3)<<4)); t&3==r0&3, s adds 4096
    const int wst = r0 * 64 + ((g0 * 16) ^ ((r0 & 3) << 4));
    const _Float16* whg = whiG + (size_t)(kbase + r0) * DIM + g0 * 8;
    const _Float16* wlg = wloG + (size_t)(kbase + r0) * DIM + g0 * 8;

    // ---- B fragment read addressing: row r=wq*128+j*16+(lane&15), k-group kg
    const int kg = lane >> 4;
    // byte = r*64 + (kg*16 ^ ((r&3)<<4)); r&3 == lane&3; j adds 1024
    const int rb = (wq * 128 + (lane & 15)) * 64 + ((kg * 16) ^ ((lane & 3) << 4));

    // ---- A direct-global base: z row tok0+wm*64+(lane&15)+i*16, cols kg*8..
    const float* zA = z + (size_t)(tok0 + wm * 64 + (lane & 15)) * DIM + kg * 8;

    half8 wh[4], wl[4];
    auto loadw = [&](int dtn) {
        #pragma unroll
        for (int s = 0; s < 4; s++) {
            wh[s] = *(const half8*)(whg + (size_t)s * 64 * DIM + dtn * 32);
            wl[s] = *(const half8*)(wlg + (size_t)s * 64 * DIM + dtn * 32);
        }
    };
    auto writew = [&](int b) {
        #pragma unroll
        for (int s = 0; s < 4; s++) {
            *(half8*)&wbuf[b][wst + s * 4096]         = wh[s];
            *(half8*)&wbuf[b][wst + s * 4096 + 16384] = wl[s];
        }
    };

    // prologue: stage w chunk 0
    loadw(0); writew(0);
    __syncthreads();

    for (int dt = 0; dt < 8; ++dt) {
        const int cur = dt & 1;
        if (dt < 7) loadw(dt + 1);      // w loads fly under A-cvt + MFMA j0..3

        // A fragments: global fp32 -> hi/lo fp16 in regs (no LDS round-trip)
        half8 ah[4], al[4];
        #pragma unroll
        for (int i = 0; i < 4; i++) {
            const float* p = zA + (size_t)i * 16 * DIM + dt * 32;
            float4 a = *(const float4*)p;
            float4 b = *(const float4*)(p + 4);
            float vals[8] = {a.x, a.y, a.z, a.w, b.x, b.y, b.z, b.w};
            #pragma unroll
            for (int e = 0; e < 8; e++) {
                _Float16 h = (_Float16)vals[e];
                ah[i][e] = h;
                al[i][e] = (_Float16)(vals[e] - (float)h);
            }
        }

        __builtin_amdgcn_s_setprio(1);
        #pragma unroll
        for (int j = 0; j < 4; j++) {
            const char* pb = &wbuf[cur][rb + j * 1024];
            half8 bh = *(const half8*)pb;
            half8 bl = *(const half8*)(pb + 16384);
            #pragma unroll
            for (int i = 0; i < 4; i++) {
                acc[i][j] = __builtin_amdgcn_mfma_f32_16x16x32_f16(ah[i], bh, acc[i][j], 0, 0, 0);
                acc[i][j] = __builtin_amdgcn_mfma_f32_16x16x32_f16(ah[i], bl, acc[i][j], 0, 0, 0);
                acc[i][j] = __builtin_amdgcn_mfma_f32_16x16x32_f16(al[i], bh, acc[i][j], 0, 0, 0);
            }
        }
        __builtin_amdgcn_s_setprio(0);

        if (dt < 7) writew(cur ^ 1);    // w regs die here (short lifetime)

        __builtin_amdgcn_s_setprio(1);
        #pragma unroll
        for (int j = 4; j < 8; j++) {
            const char* pb = &wbuf[cur][rb + j * 1024];
            half8 bh = *(const half8*)pb;
            half8 bl = *(const half8*)(pb + 16384);
            #pragma unroll
            for (int i = 0; i < 4; i++) {
                acc[i][j] = __builtin_amdgcn_mfma_f32_16x16x32_f16(ah[i], bh, acc[i][j], 0, 0, 0);
                acc[i][j] = __builtin_amdgcn_mfma_f32_16x16x32_f16(ah[i], bl, acc[i][j], 0, 0, 0);
                acc[i][j] = __builtin_amdgcn_mfma_f32_16x16x32_f16(al[i], bh, acc[i][j], 0, 0, 0);
            }
        }
        __builtin_amdgcn_s_setprio(0);

        __syncthreads();   // dt reads done everywhere; dt+1 writes visible
    }

    // epilogue: dist = wn[code] - 2*dot (||z||^2 constant per row).
    // C layout: col(code) = lane&15, row(token) = (lane>>4)*4 + reg.
    #pragma unroll
    for (int i = 0; i < 4; i++) {
        #pragma unroll
        for (int r = 0; r < 4; r++) {
            float bv = 3.4e38f; int bi = 0;
            #pragma unroll
            for (int j = 0; j < 8; j++) {
                int cl = wq * 128 + j * 16 + (lane & 15);
                float dist = wnr[j] - 2.0f * acc[i][j][r];
                if (dist < bv) { bv = dist; bi = kbase + cl; }
            }
            unsigned uu = __float_as_uint(bv);
            unsigned ss = (uu & 0x80000000u) ? ~uu : (uu | 0x80000000u);
            u64 key = ((u64)ss << 32) | (unsigned)bi;
            #pragma unroll
            for (int m = 1; m < 16; m <<= 1) {
                u64 o = __shfl_xor(key, m);
                if (o < key) key = o;
            }
            if ((lane & 15) == 0) {
                int token = tok0 + wm * 64 + i * 16 + (lane >> 4) * 4 + r;
                atomicMin(&keys[token], key);
            }
        }
    }
}

// ---------------- gather + commitment loss + idx/counts ----------------
// wave (64 lanes) = one token (64 float4). 8192 waves x 4 iters.
// k masked to 10 bits: valid keys always carry code < 1024; converts any
// upstream failure into a clean numeric mismatch instead of a wild gather
// -> memory fault -> dead container (round-1/2 lesson).
__global__ void gather_loss_kernel(const float* __restrict__ z,
                                   const float* __restrict__ w,
                                   const u64* __restrict__ keys,
                                   float* __restrict__ zq_out,
                                   float* __restrict__ idxf,
                                   int* __restrict__ counts,
                                   float* __restrict__ partials)
{
    __shared__ float red[4];
    int tid = threadIdx.x;
    int lane = tid & 63;
    int wid = blockIdx.x * 4 + (tid >> 6);   // 0..8191
    float s = 0.0f;
    #pragma unroll
    for (int it = 0; it < 4; it++) {
        int tok = wid + it * 8192;
        u64 key = 0;
        if (lane == 0) key = keys[tok];
        key = __shfl(key, 0);
        int k = (int)(key & (u64)(K_CODES - 1));
        float4 wv = *(const float4*)(w + (size_t)k * DIM + lane * 4);
        float4 zv = *(const float4*)(z + (size_t)tok * DIM + lane * 4);
        *(float4*)(zq_out + (size_t)tok * DIM + lane * 4) = wv;
        float dx = wv.x - zv.x, dy = wv.y - zv.y, dz = wv.z - zv.z, dw = wv.w - zv.w;
        s += dx * dx + dy * dy + dz * dz + dw * dw;
        if (lane == 0) {
            idxf[tok] = (float)k;
            atomicAdd(&counts[k], 1);
        }
    }
    #pragma unroll
    for (int off = 32; off; off >>= 1) s += __shfl_down(s, off);
    if (lane == 0) red[tid >> 6] = s;
    __syncthreads();
    if (tid == 0)
        partials[blockIdx.x] = red[0] + red[1] + red[2] + red[3];
}

// ---------------- perplexity + loss finalize ----------------
__global__ void finalize_kernel(const int* __restrict__ counts,
                                const float* __restrict__ partials,
                                float* __restrict__ loss_out,
                                float* __restrict__ ppl_out)
{
    __shared__ float redE[16], redL[16];
    int tid = threadIdx.x;  // 1024
    float e = (float)counts[tid] * (1.0f / (float)N_TOKENS);
    float t = -e * logf(e + 1e-10f);
    float p = partials[tid] + partials[tid + 1024];
    #pragma unroll
    for (int off = 32; off; off >>= 1) {
        t += __shfl_down(t, off);
        p += __shfl_down(p, off);
    }
    if ((tid & 63) == 0) { redE[tid >> 6] = t; redL[tid >> 6] = p; }
    __syncthreads();
    if (tid == 0) {
        float se = 0.0f, sl = 0.0f;
        #pragma unroll
        for (int i = 0; i < 16; i++) { se += redE[i]; sl += redL[i]; }
        *ppl_out = expf(se);
        *loss_out = BETA * sl / (float)((size_t)N_TOKENS * DIM);
    }
}

extern "C" void kernel_launch(void* const* d_in, const int* in_sizes, int n_in,
                              void* d_out, int out_size, void* d_ws, size_t ws_size,
                              hipStream_t stream) {
    const float* z = (const float*)d_in[0];
    const float* w = (const float*)d_in[1];
    float* out = (float*)d_out;

    // d_out layout (float): [0]=loss, [1..NT*D]=z_q_st, [..]=indices(float), [last]=perplexity
    float* loss_out = out;
    float* zq_out   = out + 1;
    float* idxf     = out + 1 + (size_t)N_TOKENS * DIM;
    float* ppl_out  = out + (out_size - 1);

    // ws layout: wn f32[1024] | counts i32[1024] | partials f32[2048]
    //            | keys u64[32768] @ byte 16384 | whiG/wloG fp16[1024*256] @ 278528
    float* wn       = (float*)d_ws;
    int*   counts   = (int*)d_ws + 1024;
    float* partials = (float*)d_ws + 2048;
    u64*   keys     = (u64*)((char*)d_ws + 16384);
    _Float16* whiG  = (_Float16*)((char*)d_ws + 16384 + (size_t)N_TOKENS * 8);
    _Float16* wloG  = whiG + (size_t)K_CODES * DIM;

    init_kernel<<<K_CODES, 64, 0, stream>>>(w, wn, counts, keys, whiG, wloG);
    argmin_kernel<<<4 * 256, 256, 0, stream>>>(z, whiG, wloG, wn, keys);
    gather_loss_kernel<<<2048, 256, 0, stream>>>(z, w, keys, zq_out, idxf, counts, partials);
    finalize_kernel<<<1, 1024, 0, stream>>>(counts, partials, loss_out, ppl_out);
}